// Round 3
// baseline (144.670 us; speedup 1.0000x reference)
//
#include <hip/hip_runtime.h>
#include <math.h>

#define HW 262144        // 512*512 elements per batch
#define BPB 32           // blocks per batch
#define CHUNK 8192       // elements per block per input stream
#define NBLK (64 * BPB)  // 2048 blocks

typedef float f4 __attribute__((ext_vector_type(4)));

// Monotonic unsigned mapping of float bits: preserves ordering for all
// finite floats (negatives flipped, positives offset).
__device__ __forceinline__ unsigned int fmono(float f) {
    unsigned int u = __float_as_uint(f);
    return (u & 0x80000000u) ? ~u : (u | 0x80000000u);
}

// R12: force the 16-deep MLP the compiler refused twice (R10: VGPR=36,
// R11: sched_barrier no-op, VGPR still 36). Volatile inline-asm
// global_load_dwordx4 (saddr = SGPR-pair block-uniform base, voffset =
// per-thread VGPR) pins issue order and register liveness by construction:
// 16 loads in flight (16KB/wave), one manual s_waitcnt vmcnt(0), then
// sched_barrier(0) so no consumer hoists above the wait (rule #18).
// Discriminates: latency/MLP-bound (dur -> ~25us) vs per-CU read-service
// cap ~12 GB/s/CU (dur unchanged -> declare roofline: per-CU read rate
// equals m13's copy READ rate of 12.3 GB/s/CU exactly).
__global__ __launch_bounds__(256, 4) void reduce_kernel(
    const float* __restrict__ pred, const float* __restrict__ label,
    unsigned long long* __restrict__ pblk, unsigned long long* __restrict__ lblk,
    float* __restrict__ sblk)
{
    const int bi = blockIdx.x;
    const int b = bi >> 5;            // batch
    const int chunk = bi & (BPB - 1);
    const int t = threadIdx.x;
    const size_t base = (size_t)b * HW + (size_t)chunk * CHUNK;

    const float* pb = pred + base;    // block-uniform -> SGPR pair
    const float* lb = label + base;   // block-uniform -> SGPR pair

    // per-thread byte offsets; stride between loads = 256 lanes*16B = 4KB
    const unsigned v0 = (unsigned)t * 16u;

    f4 p0, p1, p2, p3, p4, p5, p6, p7;
    f4 l0, l1, l2, l3, l4, l5, l6, l7;

#define GLD(dst, sbase, off)                                              \
    asm volatile("global_load_dwordx4 %0, %1, %2"                         \
                 : "=v"(dst) : "v"(off), "s"(sbase))

    // Phase 1: 16 loads issued back-to-back, all results live.
    GLD(p0, pb, v0);
    GLD(p1, pb, v0 + 4096u);
    GLD(p2, pb, v0 + 8192u);
    GLD(p3, pb, v0 + 12288u);
    GLD(p4, pb, v0 + 16384u);
    GLD(p5, pb, v0 + 20480u);
    GLD(p6, pb, v0 + 24576u);
    GLD(p7, pb, v0 + 28672u);
    GLD(l0, lb, v0);
    GLD(l1, lb, v0 + 4096u);
    GLD(l2, lb, v0 + 8192u);
    GLD(l3, lb, v0 + 12288u);
    GLD(l4, lb, v0 + 16384u);
    GLD(l5, lb, v0 + 20480u);
    GLD(l6, lb, v0 + 24576u);
    GLD(l7, lb, v0 + 28672u);
#undef GLD

    asm volatile("s_waitcnt vmcnt(0)" ::: "memory");
    __builtin_amdgcn_sched_barrier(0);   // nothing crosses the wait (rule #18)

    // Phase 2: compute (identical math to the verified R5/R9/R10 phase).
    float sumsq = 0.0f;
    float pmax = -INFINITY, lmax = -INFINITY;
    unsigned int pidx = 0, lidx = 0;
    const unsigned int ebase = (unsigned int)chunk * CHUNK + (unsigned int)t * 4u;

#define ACC(P, L, E)                                                      \
    do {                                                                  \
        const unsigned int e = (E);                                       \
        float d;                                                          \
        d = P.x - L.x; sumsq += d * d;                                    \
        d = P.y - L.y; sumsq += d * d;                                    \
        d = P.z - L.z; sumsq += d * d;                                    \
        d = P.w - L.w; sumsq += d * d;                                    \
        if (P.x > pmax) { pmax = P.x; pidx = e;      }                    \
        if (P.y > pmax) { pmax = P.y; pidx = e + 1u; }                    \
        if (P.z > pmax) { pmax = P.z; pidx = e + 2u; }                    \
        if (P.w > pmax) { pmax = P.w; pidx = e + 3u; }                    \
        if (L.x > lmax) { lmax = L.x; lidx = e;      }                    \
        if (L.y > lmax) { lmax = L.y; lidx = e + 1u; }                    \
        if (L.z > lmax) { lmax = L.z; lidx = e + 2u; }                    \
        if (L.w > lmax) { lmax = L.w; lidx = e + 3u; }                    \
    } while (0)

    ACC(p0, l0, ebase);
    ACC(p1, l1, ebase + 1024u);
    ACC(p2, l2, ebase + 2048u);
    ACC(p3, l3, ebase + 3072u);
    ACC(p4, l4, ebase + 4096u);
    ACC(p5, l5, ebase + 5120u);
    ACC(p6, l6, ebase + 6144u);
    ACC(p7, l7, ebase + 7168u);
#undef ACC

    // pack: high 32 = monotonic value bits, low 32 = ~index so that on value
    // tie the LOWER index wins under unsigned max (matches jnp.argmax).
    unsigned long long ppk = ((unsigned long long)fmono(pmax) << 32) | (unsigned long long)(0xFFFFFFFFu - pidx);
    unsigned long long lpk = ((unsigned long long)fmono(lmax) << 32) | (unsigned long long)(0xFFFFFFFFu - lidx);

    // wave(64) shuffle reduction
    for (int off = 32; off > 0; off >>= 1) {
        sumsq += __shfl_down(sumsq, off);
        unsigned long long o;
        o = __shfl_down(ppk, off); if (o > ppk) ppk = o;
        o = __shfl_down(lpk, off); if (o > lpk) lpk = o;
    }

    __shared__ float s_sum[4];
    __shared__ unsigned long long s_pp[4], s_lp[4];
    const int wave = t >> 6, lane = t & 63;
    if (lane == 0) { s_sum[wave] = sumsq; s_pp[wave] = ppk; s_lp[wave] = lpk; }
    __syncthreads();
    if (t == 0) {
        float s = s_sum[0] + s_sum[1] + s_sum[2] + s_sum[3];
        unsigned long long Pk = s_pp[0], Lk = s_lp[0];
#pragma unroll
        for (int i = 1; i < 4; ++i) {
            if (s_pp[i] > Pk) Pk = s_pp[i];
            if (s_lp[i] > Lk) Lk = s_lp[i];
        }
        // Atomic-free: every block writes its own slot (no memset, no fences).
        pblk[bi] = Pk;
        lblk[bi] = Lk;
        sblk[bi] = s;
    }
}

// One block, 1024 threads: reduces 2048 per-block partials. (Unchanged,
// harness-verified.)
__global__ __launch_bounds__(1024) void finalize_kernel(
    const unsigned long long* __restrict__ pblk,
    const unsigned long long* __restrict__ lblk,
    const float* __restrict__ sblk,
    float* __restrict__ out)
{
    const int t = threadIdx.x;  // 0..1023

    // global mse: sum of all 2048 partials
    float s = sblk[t] + sblk[t + 1024];
    for (int off = 32; off > 0; off >>= 1) s += __shfl_down(s, off);
    __shared__ float ss[16];
    const int wave = t >> 6;
    if ((t & 63) == 0) ss[wave] = s;

    // per-batch argmax over 32 chunk partials: batch = t>>4, j = t&15
    const int batch = t >> 4, j = t & 15;
    unsigned long long Pv = pblk[batch * 32 + j];
    unsigned long long o  = pblk[batch * 32 + j + 16];
    if (o > Pv) Pv = o;
    unsigned long long Lv = lblk[batch * 32 + j];
    o = lblk[batch * 32 + j + 16];
    if (o > Lv) Lv = o;
    for (int off = 8; off > 0; off >>= 1) {
        o = __shfl_down(Pv, off, 16); if (o > Pv) Pv = o;
        o = __shfl_down(Lv, off, 16); if (o > Lv) Lv = o;
    }
    __shared__ float dd[64];
    if (j == 0) {
        const unsigned int ip = 0xFFFFFFFFu - (unsigned int)(Pv & 0xFFFFFFFFull);
        const unsigned int il = 0xFFFFFFFFu - (unsigned int)(Lv & 0xFFFFFFFFull);
        const float rp = (float)(ip >> 9), cp = (float)(ip & 511u);
        const float rl = (float)(il >> 9), cl = (float)(il & 511u);
        dd[batch] = (rp - rl) * (rp - rl) + (cp - cl) * (cp - cl);
    }
    __syncthreads();
    if (t < 64) {
        float d = dd[t];
        for (int off = 32; off > 0; off >>= 1) d += __shfl_down(d, off);
        if (t == 0) {
            float m = 0.0f;
#pragma unroll
            for (int i = 0; i < 16; ++i) m += ss[i];
            const float alpha = (d != 0.0f) ? (m / d) : 1.0f;
            out[0] = (m + 0.25f * alpha * d) / 64.0f;
        }
    }
}

extern "C" void kernel_launch(void* const* d_in, const int* in_sizes, int n_in,
                              void* d_out, int out_size, void* d_ws, size_t ws_size,
                              hipStream_t stream) {
    const float* pred  = (const float*)d_in[0];
    const float* label = (const float*)d_in[1];
    float* out = (float*)d_out;

    unsigned long long* pblk = (unsigned long long*)d_ws;  // 2048 packed pred argmax
    unsigned long long* lblk = pblk + NBLK;                // 2048 packed label argmax
    float* sblk = (float*)(lblk + NBLK);                   // 2048 mse partials

    reduce_kernel<<<dim3(NBLK), dim3(256), 0, stream>>>(pred, label, pblk, lblk, sblk);
    finalize_kernel<<<dim3(1), dim3(1024), 0, stream>>>(pblk, lblk, sblk, out);
}